// Round 5
// baseline (545.262 us; speedup 1.0000x reference)
//
#include <hip/hip_runtime.h>
#include <math.h>

#define NA 16
#define NS 64
#define NB 100
#define NE 12
#define ML 20
#define DD 512
#define NC (NA*NE)   /* 192 */
#define NR (NA*NS)   /* 1024 */
#define EPSF 1e-5f
#define DELTA_F 0.2f
#define IOU_TOTAL (NA*NS*NB*ML)
#define IOU_BLOCKS ((IOU_TOTAL + 255)/256)   /* 8000 */
#define PIT 34       /* even pitch: 8B-aligned ds_read_b64; conflict-free b64 reads */
#define MIDB (NA*(NE+1))                     /* 208 waiter blocks */

// ---------- helpers ----------
__device__ inline void wave_minmax64(float v, float& mn, float& mx){
  mn = v; mx = v;
  #pragma unroll
  for (int off = 32; off > 0; off >>= 1){
    mn = fminf(mn, __shfl_xor(mn, off));
    mx = fmaxf(mx, __shfl_xor(mx, off));
  }
}

__device__ inline float block_sum256(float v, float* sred){
  int t = threadIdx.x;
  #pragma unroll
  for (int off = 32; off > 0; off >>= 1) v += __shfl_xor(v, off);
  if ((t & 63) == 0) sred[t >> 6] = v;
  __syncthreads();
  float tot = sred[0] + sred[1] + sred[2] + sred[3];
  __syncthreads();
  return tot;
}

// ---------- gemm pass: pitch-34 tiles, ds_read_b64 kk-pairs (R3's 283us recipe) ----------
template<int JC>
__device__ __forceinline__ void gemm_pass(
    const float* __restrict__ abase, const float* __restrict__ word,
    const int* __restrict__ scols, float* __restrict__ As, float* __restrict__ Bs,
    int t, int tc, int tb)
{
  float acc[7][JC];
  #pragma unroll
  for (int j = 0; j < 7; ++j)
    #pragma unroll
    for (int jc = 0; jc < JC; ++jc) acc[j][jc] = 0.f;

  for (int k0 = 0; k0 < DD; k0 += 32){
    for (int i = t; i < NB * 8; i += 256){
      int b = i >> 3, q = i & 7;
      const float4 v = *(const float4*)(abase + (size_t)b * DD + k0 + q * 4);
      float* d = &As[b * PIT + q * 4];
      *(float2*)d       = make_float2(v.x, v.y);
      *(float2*)(d + 2) = make_float2(v.z, v.w);
    }
    for (int i = t; i < JC * 16 * 8; i += 256){
      int c = i >> 3, q = i & 7;
      const float4 v = *(const float4*)(word + (size_t)scols[c] * DD + k0 + q * 4);
      float* d = &Bs[c * PIT + q * 4];
      *(float2*)d       = make_float2(v.x, v.y);
      *(float2*)(d + 2) = make_float2(v.z, v.w);
    }
    __syncthreads();
    #pragma unroll 4
    for (int kk = 0; kk < 32; kk += 2){
      float2 breg[JC], areg[7];
      #pragma unroll
      for (int jc = 0; jc < JC; ++jc)
        breg[jc] = *(const float2*)&Bs[(jc * 16 + tc) * PIT + kk];
      #pragma unroll
      for (int j = 0; j < 7; ++j){
        int b = tb * 7 + j; b = (b < NB) ? b : (NB - 1);
        areg[j] = *(const float2*)&As[b * PIT + kk];
      }
      #pragma unroll
      for (int j = 0; j < 7; ++j)
        #pragma unroll
        for (int jc = 0; jc < JC; ++jc){
          float s0 = acc[j][jc];
          s0 = fmaf(areg[j].x, breg[jc].x, s0);
          s0 = fmaf(areg[j].y, breg[jc].y, s0);
          acc[j][jc] = s0;
        }
    }
    __syncthreads();
  }
  // per-thread max/argmax over this thread's 7 rows (b ascending -> first-index tie-break)
  #pragma unroll
  for (int jc = 0; jc < JC; ++jc){
    int ci = jc * 16 + tc;
    float best = -3.4e38f; int bi = 0;
    #pragma unroll
    for (int j = 0; j < 7; ++j){
      int b = tb * 7 + j;
      if (b < NB){ float v = acc[j][jc]; if (v > best){ best = v; bi = b; } }
    }
    As[ci * 16 + tb] = best;
    Bs[ci * 16 + tb] = (float)bi;
  }
}

__device__ __forceinline__ void gemm_epilogue(
    const float* __restrict__ As, const float* __restrict__ Bs,
    const int* __restrict__ scols, int base, int ncols, int kcnt,
    float* __restrict__ dsim, float* __restrict__ dind, int r, int t)
{
  __syncthreads();
  if (t < ncols){
    int gi = base + t;
    if (gi < kcnt){
      float best = -3.4e38f; int bi = 0;
      #pragma unroll
      for (int g = 0; g < 16; ++g){       // ascending tb == ascending b -> first-index tie-break
        float v = As[t * 16 + g];
        if (v > best){ best = v; bi = (int)Bs[t * 16 + g]; }
      }
      int c = scols[gi];
      dsim[r * NC + c] = best;
      dind[r * NC + c] = (float)bi;
    }
  }
  __syncthreads();
}

// ---------- K: everything in one launch ----------
// blocks [0,NR): gemm; [NR, NR+IOU_BLOCKS): IoU; [NR+IOU_BLOCKS, +MIDB): mid roles.
// gemm block r -> fence + atomicAdd(agent_done[r>>6]). Mid role (a,y) needs ONLY
// agent a's 64 gemm blocks; waiter t0 spins on agent_done[a]==64 (device-scope RMW
// read + s_sleep). Deadlock-free: 208 waiters << resident capacity; all other
// blocks are dependency-free. Counters pre-zeroed by hipMemsetAsync.
__global__ __launch_bounds__(256) void k_all(
    const float* __restrict__ vis, const float* __restrict__ word,
    const int* __restrict__ elen, const float* __restrict__ boxes,
    const float* __restrict__ det,
    float* __restrict__ dind, float* __restrict__ dsim, float* __restrict__ dtin,
    float* __restrict__ sf, float* __restrict__ accums,
    unsigned int* __restrict__ agent_done, unsigned int* __restrict__ mid_done,
    float* __restrict__ out)
{
  const int t = threadIdx.x;
  const unsigned bx = blockIdx.x;

  if (bx >= NR && bx < NR + IOU_BLOCKS){
    // ---- IoU path ----
    int idx = (int)(bx - NR) * 256 + t;
    if (idx < IOU_TOTAL){
      int m = idx % ML; int t2 = idx / ML; int b = t2 % NB; int t3 = t2 / NB;
      const float4 A = *(const float4*)(boxes + (size_t)(t3 * NB + b) * 4);
      int a = t3 / NS;
      const float4 B = *(const float4*)(det + (size_t)(a * ML + m) * 4);
      float iw = fminf(A.z, B.z) - fmaxf(A.x, B.x);
      float ih = fminf(A.w, B.w) - fmaxf(A.y, B.y);
      bool pos = (iw > 0.f) && (ih > 0.f);
      float inter = pos ? iw * ih : 0.f;
      float a1 = (A.z - A.x) * (A.w - A.y);
      float a2 = (B.z - B.x) * (B.w - B.y);
      float den = a1 + a2 - inter;
      dtin[idx] = pos ? inter / (den > 0.f ? den : 1.f) : 0.f;
    }
    return;
  }

  __shared__ float As[NB * PIT];      // 3400 floats; gemm tiles / redv
  __shared__ float Bs[128 * PIT];     // 4352 floats; gemm tiles / redi
  __shared__ int   scols[NC];
  __shared__ int   s_el[NA];
  __shared__ int   s_cnt;
  __shared__ float sred[4];
  __shared__ int   s_mi[NS];
  __shared__ float s_inv[NS];
  __shared__ float s_nw2[NS];
  __shared__ float s_sn[NS];
  __shared__ int   s_last;

  if (bx < NR){
    // ================= GEMM path =================
    const int r  = bx;
    const int tc = t & 15;
    const int tb = t >> 4;

    if (t < NA){ int L = elen[t]; L = L < 0 ? 0 : (L > NE ? NE : L); s_el[t] = L; }
    if (t < NC){ dsim[r * NC + t] = 0.f; dind[r * NC + t] = 0.f; }
    __syncthreads();
    if (t < NC){
      int aw = t / NE, e = t - aw * NE;
      int base = 0;
      #pragma unroll
      for (int i = 0; i < NA; ++i) base += (i < aw) ? s_el[i] : 0;
      if (e < s_el[aw]) scols[base + e] = t;
    }
    if (t == 0){
      int n = 0;
      #pragma unroll
      for (int i = 0; i < NA; ++i) n += s_el[i];
      s_cnt = n;
    }
    __syncthreads();
    const int kcnt = s_cnt;
    if (t < NC && t >= kcnt) scols[t] = (kcnt > 0) ? scols[kcnt - 1] : 0;
    __syncthreads();

    const int jcnt = (kcnt + 15) >> 4;
    if (jcnt > 0){
      const float* abase = vis + (size_t)r * NB * DD;
      const int jc1 = (jcnt > 8) ? 8 : jcnt;
      switch (jc1){
        case 1: gemm_pass<1>(abase, word, scols, As, Bs, t, tc, tb); break;
        case 2: gemm_pass<2>(abase, word, scols, As, Bs, t, tc, tb); break;
        case 3: gemm_pass<3>(abase, word, scols, As, Bs, t, tc, tb); break;
        case 4: gemm_pass<4>(abase, word, scols, As, Bs, t, tc, tb); break;
        case 5: gemm_pass<5>(abase, word, scols, As, Bs, t, tc, tb); break;
        case 6: gemm_pass<6>(abase, word, scols, As, Bs, t, tc, tb); break;
        case 7: gemm_pass<7>(abase, word, scols, As, Bs, t, tc, tb); break;
        default: gemm_pass<8>(abase, word, scols, As, Bs, t, tc, tb); break;
      }
      gemm_epilogue(As, Bs, scols, 0, jc1 * 16, kcnt, dsim, dind, r, t);
      if (jcnt > 8){
        const int jc2 = jcnt - 8;
        switch (jc2){
          case 1: gemm_pass<1>(abase, word, scols + 128, As, Bs, t, tc, tb); break;
          case 2: gemm_pass<2>(abase, word, scols + 128, As, Bs, t, tc, tb); break;
          case 3: gemm_pass<3>(abase, word, scols + 128, As, Bs, t, tc, tb); break;
          default: gemm_pass<4>(abase, word, scols + 128, As, Bs, t, tc, tb); break;
        }
        gemm_epilogue(As, Bs, scols, 128, jc2 * 16, kcnt, dsim, dind, r, t);
      }
    }
    // ticket: this agent's dsim/dind rows are complete
    __syncthreads();
    if (t == 0){
      __threadfence();
      atomicAdd(&agent_done[r >> 6], 1u);
    }
    return;
  }

  // ================= MID-ROLE path (waiters) =================
  const int w_id = (int)(bx - NR - IOU_BLOCKS);
  const int a = w_id / (NE + 1), y = w_id % (NE + 1);
  const int lane = t & 63, w = t >> 6;

  if (t == 0){
    while (atomicAdd(&agent_done[a], 0u) < (unsigned)NS)   // device-scope RMW read
      __builtin_amdgcn_s_sleep(8);
    __threadfence();                                        // acquire
  }
  __syncthreads();

  if (y == NE){
    // ---- sf role: column-normalize D_sim over s, fold into Sf. wave w -> aw = w,w+4,...
    for (int aw = w; aw < NA; aw += 4){
      float accv = 0.f;
      for (int e = 0; e < NE; ++e){
        int c = aw * NE + e;
        float v = dsim[(a * NS + lane) * NC + c];
        float mn, mx; wave_minmax64(v, mn, mx);
        accv += v * (v - mn) / (mx - mn + EPSF);
      }
      float dv = fmaxf((float)elen[aw], 1.f);
      sf[(a * NS + lane) * NA + aw] = accv / dv;
    }
  } else {
    const int e = y;
    if (e < elen[a]){
      // ---- gram role: vis_loss via ||sum w||^2 identity; simn computed in-block
      if (w == 0){
        float v = dsim[(a * NS + lane) * NC + (a * NE + e)];
        float mn, mx; wave_minmax64(v, mn, mx);
        s_sn[lane] = (v - mn) / (mx - mn + EPSF);
      }
      if (t < NS) s_mi[t] = (int)dind[(size_t)(a * NS + t) * NC + (a * NE + e)];
      __syncthreads();

      for (int s = w; s < NS; s += 4){
        const float* row = vis + (size_t)((a * NS + s) * NB + s_mi[s]) * DD;
        float4 v0 = *(const float4*)(row + lane * 8);
        float4 v1 = *(const float4*)(row + lane * 8 + 4);
        float ss = v0.x*v0.x + v0.y*v0.y + v0.z*v0.z + v0.w*v0.w
                 + v1.x*v1.x + v1.y*v1.y + v1.z*v1.z + v1.w*v1.w;
        #pragma unroll
        for (int off = 32; off > 0; off >>= 1) ss += __shfl_xor(ss, off);
        if (lane == 0){
          float sn = s_sn[s];
          float d = sqrtf(ss) + EPSF;
          s_inv[s] = sn / d;
          s_nw2[s] = sn * sn * ss / (d * d);
        }
      }
      __syncthreads();

      float W0 = 0.f, W1 = 0.f;
      #pragma unroll 8
      for (int s = 0; s < NS; ++s){
        const float* row = vis + (size_t)((a * NS + s) * NB + s_mi[s]) * DD;
        float inv = s_inv[s];
        W0 = fmaf(row[t],       inv, W0);
        W1 = fmaf(row[t + 256], inv, W1);
      }
      float w2  = block_sum256(W0 * W0 + W1 * W1, sred);
      float nw2 = block_sum256((t < NS) ? s_nw2[t] : 0.f, sred);
      if (t == 0){
        float part = (float)(NS * (NS - 1)) - w2 + nw2;
        atomicAdd(&accums[0], part);
        atomicAdd(&accums[1], (float)(NS * (NS - 1)));
      }
    }
  }

  // ---- completion: last role block runs the final reduction (R3's proven pattern) ----
  __syncthreads();
  if (t == 0){
    __threadfence();
    unsigned int old = atomicAdd(mid_done, 1u);
    s_last = (old == (unsigned int)(MIDB - 1)) ? 1 : 0;
  }
  __syncthreads();
  if (s_last){
    __threadfence();
    float sum = 0.f;
    for (int i = t; i < NA * NS * NA; i += 256){
      int b = i & (NA - 1);
      int a2 = i >> 10;
      int s2 = (i >> 4) & (NS - 1);
      float v  = sf[i];
      float d1 = sf[(b * NS + s2) * NA + b];
      float d2 = sf[(a2 * NS + s2) * NA + a2];
      sum += fmaxf(v - d1 + DELTA_F, 0.f) + fmaxf(v - d2 + DELTA_F, 0.f);
    }
    float tot = block_sum256(sum, sred);
    if (t == 0){
      float frame = tot / (float)(NA * NA * NS);
      float cnt = accums[1];
      float vis_loss = accums[0] / fmaxf(cnt, 1.f);
      out[0] = (frame + vis_loss) * 10.f;
    }
  }
}

// ---------- launch ----------
extern "C" void kernel_launch(void* const* d_in, const int* in_sizes, int n_in,
                              void* d_out, int out_size, void* d_ws, size_t ws_size,
                              hipStream_t stream)
{
  const float* vis   = (const float*)d_in[0];
  const float* word  = (const float*)d_in[1];
  const float* boxes = (const float*)d_in[2];
  const float* det   = (const float*)d_in[3];
  const int*   elen  = (const int*)d_in[4];

  float* out   = (float*)d_out;
  float* dind  = out;                       // 196608 (indices as float)
  float* dsim  = out + NR * NC;             // 196608
  float* mloss = out + 2 * NR * NC;         // 1
  float* dtin  = mloss + 1;                 // 2,048,000

  float* ws     = (float*)d_ws;
  float* sf     = ws;                       // 16*64*16 = 16384 floats
  float* accums = ws + NA * NS * NA;        // 2 floats
  unsigned int* agent_done = (unsigned int*)(accums + 2);   // 16
  unsigned int* mid_done   = agent_done + NA;               // 1

  hipMemsetAsync(accums, 0, (2 + NA + 1) * sizeof(float), stream);
  k_all<<<NR + IOU_BLOCKS + MIDB, 256, 0, stream>>>(
      vis, word, elen, boxes, det, dind, dsim, dtin,
      sf, accums, agent_done, mid_done, mloss);
}

// Round 6
// 440.135 us; speedup vs baseline: 1.2388x; 1.2388x over previous
//
#include <hip/hip_runtime.h>
#include <math.h>

#define NA 16
#define NS 64
#define NB 100
#define NE 12
#define ML 20
#define DD 512
#define NC (NA*NE)   /* 192 */
#define NR (NA*NS)   /* 1024 */
#define EPSF 1e-5f
#define DELTA_F 0.2f
#define IOU_TOTAL (NA*NS*NB*ML)
#define IOU_BLOCKS ((IOU_TOTAL + 255)/256)   /* 8000 */
#define MID_BLOCKS (NA*(NE+1))               /* 208 */

#define ABUF 3328    /* floats: 104 rows x 32 (13 wave-loads x 8 rows) */
#define BBUF 4096    /* floats: 128 rows x 32 */
#define TBUF (ABUF + BBUF)                    /* 7424 floats per buffer */

// ---------- helpers ----------
__device__ inline void wave_minmax64(float v, float& mn, float& mx){
  mn = v; mx = v;
  #pragma unroll
  for (int off = 32; off > 0; off >>= 1){
    mn = fminf(mn, __shfl_xor(mn, off));
    mx = fmaxf(mx, __shfl_xor(mx, off));
  }
}

__device__ inline float block_sum256(float v, float* sred){
  int t = threadIdx.x;
  #pragma unroll
  for (int off = 32; off > 0; off >>= 1) v += __shfl_xor(v, off);
  if ((t & 63) == 0) sred[t >> 6] = v;
  __syncthreads();
  float tot = sred[0] + sred[1] + sred[2] + sred[3];
  __syncthreads();
  return tot;
}

// per-wave counted vmcnt wait (wave-uniform n); assembler encodes the field
__device__ __forceinline__ void wait_vmcnt(int n){
  switch (n){
    case 0: asm volatile("s_waitcnt vmcnt(0)" ::: "memory"); break;
    case 1: asm volatile("s_waitcnt vmcnt(1)" ::: "memory"); break;
    case 2: asm volatile("s_waitcnt vmcnt(2)" ::: "memory"); break;
    case 3: asm volatile("s_waitcnt vmcnt(3)" ::: "memory"); break;
    case 4: asm volatile("s_waitcnt vmcnt(4)" ::: "memory"); break;
    case 5: asm volatile("s_waitcnt vmcnt(5)" ::: "memory"); break;
    case 6: asm volatile("s_waitcnt vmcnt(6)" ::: "memory"); break;
    case 7: asm volatile("s_waitcnt vmcnt(7)" ::: "memory"); break;
    default: asm volatile("s_waitcnt vmcnt(8)" ::: "memory"); break;
  }
}

#define GLOAD_LDS(gp, lp) \
  __builtin_amdgcn_global_load_lds( \
      (const __attribute__((address_space(1))) void*)(gp), \
      (__attribute__((address_space(3))) void*)(lp), 16, 0, 0)

// ---------- gemm pass: global_load_lds dbuf + counted vmcnt + XOR-swizzled tiles ----------
// LDS layout: rows of 32 floats, chunk c (16B) of logical row r stored at physical
// chunk c ^ (r&7). Source pre-swizzle = read swizzle (involution, rule 21).
// fmaf chain identical to R2/R3 -> bit-identical outputs.
template<int JC>
__device__ __forceinline__ void gemm_pass(
    const float* __restrict__ abase, const float* __restrict__ word,
    const int* __restrict__ scols, float (*Tile)[TBUF],
    int t, int tc, int tb)
{
  constexpr int NL = 13 + 2*JC;          // wave-loads per k0-slice (8 rows each)
  constexpr int NSLOT = (NL + 3) >> 2;   // max slots per wave
  const int l = t & 63, w4 = t >> 6;
  const int sub = l >> 3, q = l & 7;

  // per-slot global float-offsets and LDS float-offsets (statically indexed)
  int goff[NSLOT]; int ldso[NSLOT];
  #pragma unroll
  for (int s = 0; s < NSLOT; ++s){
    int L = w4 + 4*s;
    goff[s] = 0; ldso[s] = 0;
    if (L < NL){
      if (L < 13){
        int rb = L*8 + sub;
        int rbs = rb < NB ? rb : NB-1;           // overflow rows: in-bounds dup, never read
        goff[s] = rbs*DD + ((q ^ (rb & 7)) << 2);
        ldso[s] = L * 256;
      } else {
        int cb = (L-13)*8 + sub;
        goff[s] = scols[cb]*DD + ((q ^ (cb & 7)) << 2);
        ldso[s] = ABUF + (L-13) * 256;
      }
    }
  }
  const int nown = (NL - w4 + 3) >> 2;   // this wave's loads per slice (uniform)

  float acc[7][JC];
  #pragma unroll
  for (int j = 0; j < 7; ++j)
    #pragma unroll
    for (int jc = 0; jc < JC; ++jc) acc[j][jc] = 0.f;

  // prologue: stage slice 0 into Tile[0]
  #pragma unroll
  for (int s = 0; s < NSLOT; ++s){
    int L = w4 + 4*s;
    if (L < NL){
      const float* g = (L < 13 ? abase : word) + goff[s];
      GLOAD_LDS(g, &Tile[0][ldso[s]]);
    }
  }

  int cur = 0;
  const int tcx = tc & 7;
  for (int k0 = 0; k0 < DD; k0 += 32){
    if (k0 + 32 < DD){
      // issue next slice into the other buffer (lands during compute below)
      #pragma unroll
      for (int s = 0; s < NSLOT; ++s){
        int L = w4 + 4*s;
        if (L < NL){
          const float* g = (L < 13 ? abase : word) + goff[s] + (k0 + 32);
          GLOAD_LDS(g, &Tile[cur^1][ldso[s]]);
        }
      }
      wait_vmcnt(nown);                  // wait only for THIS slice's loads
    } else {
      wait_vmcnt(0);
    }
    __builtin_amdgcn_sched_barrier(0);
    __builtin_amdgcn_s_barrier();
    __builtin_amdgcn_sched_barrier(0);

    const float* As = &Tile[cur][0];
    const float* Bs = &Tile[cur][ABUF];
    #pragma unroll 4
    for (int kk = 0; kk < 32; kk += 2){
      const int j = kk >> 2, r2 = kk & 3;        // 16B chunk + intra-chunk pair
      float2 breg[JC], areg[7];
      #pragma unroll
      for (int jc = 0; jc < JC; ++jc)
        breg[jc] = *(const float2*)&Bs[(jc*16 + tc)*32 + ((j ^ tcx) << 2) + r2];
      #pragma unroll
      for (int jj = 0; jj < 7; ++jj){
        int b = tb*7 + jj; b = (b < NB) ? b : (NB-1);
        areg[jj] = *(const float2*)&As[b*32 + ((j ^ (b & 7)) << 2) + r2];
      }
      #pragma unroll
      for (int jj = 0; jj < 7; ++jj)
        #pragma unroll
        for (int jc = 0; jc < JC; ++jc){
          float s0 = acc[jj][jc];
          s0 = fmaf(areg[jj].x, breg[jc].x, s0);
          s0 = fmaf(areg[jj].y, breg[jc].y, s0);
          acc[jj][jc] = s0;
        }
    }
    __builtin_amdgcn_sched_barrier(0);
    __builtin_amdgcn_s_barrier();        // all reads done before buffer re-targeted
    cur ^= 1;
  }

  // per-thread max/argmax over this thread's 7 rows (b ascending -> first-index tie-break)
  float* redv = &Tile[0][0];             // 3072 <= 3328
  float* redi = &Tile[0][ABUF];          // 3072 <= 4096
  #pragma unroll
  for (int jc = 0; jc < JC; ++jc){
    int ci = jc * 16 + tc;
    float best = -3.4e38f; int bi = 0;
    #pragma unroll
    for (int jj = 0; jj < 7; ++jj){
      int b = tb * 7 + jj;
      if (b < NB){ float v = acc[jj][jc]; if (v > best){ best = v; bi = b; } }
    }
    redv[ci * 16 + tb] = best;
    redi[ci * 16 + tb] = (float)bi;
  }
}

__device__ __forceinline__ void gemm_epilogue(
    const float* __restrict__ redv, const float* __restrict__ redi,
    const int* __restrict__ scols, int base, int ncols, int kcnt,
    float* __restrict__ dsim, float* __restrict__ dind, int r, int t)
{
  __syncthreads();
  if (t < ncols){
    int gi = base + t;
    if (gi < kcnt){
      float best = -3.4e38f; int bi = 0;
      #pragma unroll
      for (int g = 0; g < 16; ++g){       // ascending tb == ascending b -> first-index tie-break
        float v = redv[t * 16 + g];
        if (v > best){ best = v; bi = (int)redi[t * 16 + g]; }
      }
      int c = scols[gi];
      dsim[r * NC + c] = best;
      dind[r * NC + c] = (float)bi;
    }
  }
  __syncthreads();
}

// ---------- K1: fused {active-col GEMM+max/argmax} + {IoU tail blocks} ----------
__global__ __launch_bounds__(256) void k_main(
    const float* __restrict__ vis, const float* __restrict__ word,
    const int* __restrict__ elen, const float* __restrict__ boxes,
    const float* __restrict__ det,
    float* __restrict__ dind, float* __restrict__ dsim, float* __restrict__ dtin,
    float* __restrict__ accums, unsigned int* __restrict__ done)
{
  const int t = threadIdx.x;

  if (blockIdx.x >= NR){
    // ---- IoU path (memory-bound, overlaps with gemm blocks) ----
    int idx = (int)(blockIdx.x - NR) * 256 + t;
    if (idx < IOU_TOTAL){
      int m = idx % ML; int t2 = idx / ML; int b = t2 % NB; int t3 = t2 / NB;
      const float4 A = *(const float4*)(boxes + (size_t)(t3 * NB + b) * 4);
      int a = t3 / NS;
      const float4 B = *(const float4*)(det + (size_t)(a * ML + m) * 4);
      float iw = fminf(A.z, B.z) - fmaxf(A.x, B.x);
      float ih = fminf(A.w, B.w) - fmaxf(A.y, B.y);
      bool pos = (iw > 0.f) && (ih > 0.f);
      float inter = pos ? iw * ih : 0.f;
      float a1 = (A.z - A.x) * (A.w - A.y);
      float a2 = (B.z - B.x) * (B.w - B.y);
      float den = a1 + a2 - inter;
      dtin[idx] = pos ? inter / (den > 0.f ? den : 1.f) : 0.f;
    }
    return;
  }

  // ---- GEMM path ----
  __shared__ float Tile[2][TBUF];     // 59392 B, double-buffered A+B tiles
  __shared__ int   scols[NC];
  __shared__ int   s_el[NA];
  __shared__ int   s_cnt;
  const int r  = blockIdx.x;
  const int tc = t & 15;
  const int tb = t >> 4;

  if (r == 0 && t == 0){ accums[0] = 0.f; accums[1] = 0.f; done[0] = 0u; }

  if (t < NA){ int L = elen[t]; L = L < 0 ? 0 : (L > NE ? NE : L); s_el[t] = L; }
  // masked columns: S_=0 everywhere -> max 0, argmax 0. Pre-fill all, overwrite active.
  if (t < NC){ dsim[r * NC + t] = 0.f; dind[r * NC + t] = 0.f; }
  __syncthreads();
  if (t < NC){
    int aw = t / NE, e = t - aw * NE;
    int base = 0;
    #pragma unroll
    for (int i = 0; i < NA; ++i) base += (i < aw) ? s_el[i] : 0;
    if (e < s_el[aw]) scols[base + e] = t;
  }
  if (t == 0){
    int n = 0;
    #pragma unroll
    for (int i = 0; i < NA; ++i) n += s_el[i];
    s_cnt = n;
  }
  __syncthreads();
  const int kcnt = s_cnt;
  if (t < NC && t >= kcnt) scols[t] = (kcnt > 0) ? scols[kcnt - 1] : 0;  // pad tail
  __syncthreads();

  const int jcnt = (kcnt + 15) >> 4;
  if (jcnt == 0) return;              // uniform: all columns masked, zeros already written
  const float* abase = vis + (size_t)r * NB * DD;

  const int jc1 = (jcnt > 8) ? 8 : jcnt;
  switch (jc1){
    case 1: gemm_pass<1>(abase, word, scols, Tile, t, tc, tb); break;
    case 2: gemm_pass<2>(abase, word, scols, Tile, t, tc, tb); break;
    case 3: gemm_pass<3>(abase, word, scols, Tile, t, tc, tb); break;
    case 4: gemm_pass<4>(abase, word, scols, Tile, t, tc, tb); break;
    case 5: gemm_pass<5>(abase, word, scols, Tile, t, tc, tb); break;
    case 6: gemm_pass<6>(abase, word, scols, Tile, t, tc, tb); break;
    case 7: gemm_pass<7>(abase, word, scols, Tile, t, tc, tb); break;
    default: gemm_pass<8>(abase, word, scols, Tile, t, tc, tb); break;
  }
  gemm_epilogue(&Tile[0][0], &Tile[0][ABUF], scols, 0, jc1 * 16, kcnt, dsim, dind, r, t);

  if (jcnt > 8){                      // cold path (needs sum(elen) > 128)
    const int jc2 = jcnt - 8;         // 1..3
    switch (jc2){
      case 1: gemm_pass<1>(abase, word, scols + 128, Tile, t, tc, tb); break;
      case 2: gemm_pass<2>(abase, word, scols + 128, Tile, t, tc, tb); break;
      default: gemm_pass<3>(abase, word, scols + 128, Tile, t, tc, tb); break;
    }
    gemm_epilogue(&Tile[0][0], &Tile[0][ABUF], scols, 128, jc2 * 16, kcnt, dsim, dind, r, t);
  }
}

// ---------- K2: fused {Sf columns} + {vis_loss blocks} + last-block final reduction ----------
__global__ __launch_bounds__(256) void k_mid(
    const float* __restrict__ vis, const float* __restrict__ dind,
    const float* __restrict__ dsim, const int* __restrict__ elen,
    float* __restrict__ sf, float* __restrict__ accums,
    unsigned int* __restrict__ done, float* __restrict__ out)
{
  const int a = blockIdx.x, y = blockIdx.y;
  const int t = threadIdx.x, lane = t & 63, w = t >> 6;
  __shared__ float sred[4];
  __shared__ int   s_mi[NS];
  __shared__ float s_inv[NS];
  __shared__ float s_nw2[NS];
  __shared__ float s_sn[NS];
  __shared__ int   s_last;

  if (y == NE){
    // ---- sf role: column-normalize D_sim over s, fold into Sf. wave w -> aw = w,w+4,...
    for (int aw = w; aw < NA; aw += 4){
      float accv = 0.f;
      for (int e = 0; e < NE; ++e){
        int c = aw * NE + e;
        float v = dsim[(a * NS + lane) * NC + c];
        float mn, mx; wave_minmax64(v, mn, mx);
        accv += v * (v - mn) / (mx - mn + EPSF);
      }
      float dv = fmaxf((float)elen[aw], 1.f);
      sf[(a * NS + lane) * NA + aw] = accv / dv;
    }
  } else {
    const int e = y;
    if (e < elen[a]){
      // ---- gram role: vis_loss via ||sum w||^2 identity; simn computed in-block
      if (w == 0){
        float v = dsim[(a * NS + lane) * NC + (a * NE + e)];
        float mn, mx; wave_minmax64(v, mn, mx);
        s_sn[lane] = (v - mn) / (mx - mn + EPSF);
      }
      if (t < NS) s_mi[t] = (int)dind[(size_t)(a * NS + t) * NC + (a * NE + e)];
      __syncthreads();

      for (int s = w; s < NS; s += 4){
        const float* row = vis + (size_t)((a * NS + s) * NB + s_mi[s]) * DD;
        float4 v0 = *(const float4*)(row + lane * 8);
        float4 v1 = *(const float4*)(row + lane * 8 + 4);
        float ss = v0.x*v0.x + v0.y*v0.y + v0.z*v0.z + v0.w*v0.w
                 + v1.x*v1.x + v1.y*v1.y + v1.z*v1.z + v1.w*v1.w;
        #pragma unroll
        for (int off = 32; off > 0; off >>= 1) ss += __shfl_xor(ss, off);
        if (lane == 0){
          float sn = s_sn[s];
          float d = sqrtf(ss) + EPSF;
          s_inv[s] = sn / d;
          s_nw2[s] = sn * sn * ss / (d * d);
        }
      }
      __syncthreads();

      float W0 = 0.f, W1 = 0.f;
      #pragma unroll 8
      for (int s = 0; s < NS; ++s){
        const float* row = vis + (size_t)((a * NS + s) * NB + s_mi[s]) * DD;
        float inv = s_inv[s];
        W0 = fmaf(row[t],       inv, W0);
        W1 = fmaf(row[t + 256], inv, W1);
      }
      float w2  = block_sum256(W0 * W0 + W1 * W1, sred);
      float nw2 = block_sum256((t < NS) ? s_nw2[t] : 0.f, sred);
      if (t == 0){
        float part = (float)(NS * (NS - 1)) - w2 + nw2;
        atomicAdd(&accums[0], part);
        atomicAdd(&accums[1], (float)(NS * (NS - 1)));
      }
    }
  }

  // ---- completion: last role block runs the final reduction ----
  __syncthreads();
  if (t == 0){
    __threadfence();
    unsigned int old = atomicAdd(done, 1u);
    s_last = (old == (unsigned int)(MID_BLOCKS - 1)) ? 1 : 0;
  }
  __syncthreads();
  if (s_last){
    __threadfence();
    float sum = 0.f;
    for (int i = t; i < NA * NS * NA; i += 256){
      int b = i & (NA - 1);
      int a2 = i >> 10;
      int s2 = (i >> 4) & (NS - 1);
      float v  = sf[i];
      float d1 = sf[(b * NS + s2) * NA + b];
      float d2 = sf[(a2 * NS + s2) * NA + a2];
      sum += fmaxf(v - d1 + DELTA_F, 0.f) + fmaxf(v - d2 + DELTA_F, 0.f);
    }
    float tot = block_sum256(sum, sred);
    if (t == 0){
      float frame = tot / (float)(NA * NA * NS);
      float cnt = accums[1];
      float vis_loss = accums[0] / fmaxf(cnt, 1.f);
      out[0] = (frame + vis_loss) * 10.f;
    }
  }
}

// ---------- launch ----------
extern "C" void kernel_launch(void* const* d_in, const int* in_sizes, int n_in,
                              void* d_out, int out_size, void* d_ws, size_t ws_size,
                              hipStream_t stream)
{
  const float* vis   = (const float*)d_in[0];
  const float* word  = (const float*)d_in[1];
  const float* boxes = (const float*)d_in[2];
  const float* det   = (const float*)d_in[3];
  const int*   elen  = (const int*)d_in[4];

  float* out   = (float*)d_out;
  float* dind  = out;                       // 196608 (indices as float)
  float* dsim  = out + NR * NC;             // 196608
  float* mloss = out + 2 * NR * NC;         // 1
  float* dtin  = mloss + 1;                 // 2,048,000

  float* ws     = (float*)d_ws;
  float* sf     = ws;                       // 16*64*16 = 16384 floats
  float* accums = ws + NA * NS * NA;        // 2 floats
  unsigned int* done = (unsigned int*)(accums + 2);

  k_main<<<NR + IOU_BLOCKS, 256, 0, stream>>>(vis, word, elen, boxes, det,
                                              dind, dsim, dtin, accums, done);
  k_mid<<<dim3(NA, NE + 1), 256, 0, stream>>>(vis, dind, dsim, elen,
                                              sf, accums, done, mloss);
}